// Round 1
// baseline (414.783 us; speedup 1.0000x reference)
//
#include <hip/hip_runtime.h>

#define BB 16
#define QQ 900
#define CC 92
#define TT 100
#define INFF 1e18f
#define HT 256   // hungarian block threads

// ---------------- cost kernel: one block per (b,q) ----------------
__global__ __launch_bounds__(128) void cost_kernel(
    const float* __restrict__ logits,   // [B][Q][C]
    const float* __restrict__ pboxes,   // [B][Q][4]
    const int*   __restrict__ tlabels,  // [B][T]
    const float* __restrict__ tboxes,   // [B][T][4]
    float* __restrict__ cost,           // [B][Q][T]
    float* __restrict__ costT)          // [B][T][Q] or nullptr
{
  const int bq  = blockIdx.x;          // b*QQ + q
  const int b   = bq / QQ;
  const int q   = bq - b * QQ;
  const int tid = threadIdx.x;

  __shared__ float sl[CC];
  __shared__ float red[128];
  __shared__ float s_max, s_sum;

  float lv = (tid < CC) ? logits[(size_t)bq * CC + tid] : -3.402823466e38f;
  if (tid < CC) sl[tid] = lv;
  red[tid] = lv;
  __syncthreads();
  for (int s = 64; s > 0; s >>= 1) {
    if (tid < s) red[tid] = fmaxf(red[tid], red[tid + s]);
    __syncthreads();
  }
  if (tid == 0) s_max = red[0];
  __syncthreads();

  float e = (tid < CC) ? expf(lv - s_max) : 0.0f;
  if (tid < CC) sl[tid] = e;           // sl now holds exp(l - max)
  red[tid] = e;
  __syncthreads();
  for (int s = 64; s > 0; s >>= 1) {
    if (tid < s) red[tid] += red[tid + s];
    __syncthreads();
  }
  if (tid == 0) s_sum = red[0];
  __syncthreads();

  const float4 pbv = ((const float4*)pboxes)[bq];
  const float pax1 = pbv.x - 0.5f * pbv.z, pay1 = pbv.y - 0.5f * pbv.w;
  const float pax2 = pbv.x + 0.5f * pbv.z, pay2 = pbv.y + 0.5f * pbv.w;
  const float area_a = (pax2 - pax1) * (pay2 - pay1);
  const float ssum = s_sum;

  for (int t = tid; t < TT; t += 128) {
    const int lab = tlabels[b * TT + t];
    const float cc = -(sl[lab] / ssum);

    const float4 tb = ((const float4*)tboxes)[b * TT + t];
    const float cbox = fabsf(pbv.x - tb.x) + fabsf(pbv.y - tb.y) +
                       fabsf(pbv.z - tb.z) + fabsf(pbv.w - tb.w);

    const float bx1 = tb.x - 0.5f * tb.z, by1 = tb.y - 0.5f * tb.w;
    const float bx2 = tb.x + 0.5f * tb.z, by2 = tb.y + 0.5f * tb.w;
    const float area_b = (bx2 - bx1) * (by2 - by1);

    const float ltx = fmaxf(pax1, bx1), lty = fmaxf(pay1, by1);
    const float rbx = fminf(pax2, bx2), rby = fminf(pay2, by2);
    const float iw = fmaxf(rbx - ltx, 0.0f), ih = fmaxf(rby - lty, 0.0f);
    const float inter = iw * ih;
    const float uni = area_a + area_b - inter;
    const float iou = inter / uni;

    const float cx1 = fminf(pax1, bx1), cy1 = fminf(pay1, by1);
    const float cx2 = fmaxf(pax2, bx2), cy2 = fmaxf(pay2, by2);
    const float cw = fmaxf(cx2 - cx1, 0.0f), ch = fmaxf(cy2 - cy1, 0.0f);
    const float ac = cw * ch;
    const float giou = iou - (ac - uni) / ac;

    const float cval = 5.0f * cbox + cc - 2.0f * giou;
    cost[(size_t)bq * TT + t] = cval;
    if (costT) costT[((size_t)b * TT + t) * QQ + q] = cval;
  }
}

// ---------------- hungarian kernel: one block per batch ----------------
__global__ __launch_bounds__(HT) void hungarian_kernel(
    const float* __restrict__ cost,    // [B][Q][T]
    const float* __restrict__ costT,   // [B][T][Q] or nullptr
    float* __restrict__ out_q,         // [B][T]
    float* __restrict__ out_t)         // [B][T]
{
  const int b   = blockIdx.x;
  const int tid = threadIdx.x;

  __shared__ float v[QQ];
  __shared__ float u[TT + 1];
  __shared__ float minv[QQ];
  __shared__ int   way[QQ];
  __shared__ int   p[QQ + 1];
  __shared__ unsigned char used[QQ + 1];
  __shared__ int   qpt[TT];
  __shared__ float rv[HT];
  __shared__ int   ri[HT];
  __shared__ int   j0_s, i0_s, j1_s, done_s;

  for (int j = tid; j <= QQ; j += HT) {
    p[j] = TT;
    if (j < QQ) v[j] = 0.0f;
  }
  for (int i = tid; i <= TT; i += HT) u[i] = 0.0f;
  __syncthreads();

  for (int i = 0; i < TT; ++i) {
    if (tid == 0) { p[QQ] = i; j0_s = QQ; used[QQ] = 0; }
    for (int j = tid; j < QQ; j += HT) { minv[j] = INFF; way[j] = 0; used[j] = 0; }
    __syncthreads();

    while (true) {
      if (tid == 0) {
        const int j0 = j0_s;
        if (p[j0] == TT) {
          done_s = 1;
        } else {
          done_s = 0;
          used[j0] = 1;
          i0_s = p[j0];
        }
      }
      __syncthreads();
      if (done_s) break;

      const int   i0  = i0_s;
      const int   j0  = j0_s;
      const float ui0 = u[i0];

      float lmin = INFF;
      int   lidx = QQ;
      if (costT) {
        const float* __restrict__ crow = costT + ((size_t)b * TT + i0) * QQ;
        for (int j = tid; j < QQ; j += HT) {
          if (!used[j]) {
            const float cur = crow[j] - ui0 - v[j];
            float mv = minv[j];
            if (cur < mv) { mv = cur; minv[j] = cur; way[j] = j0; }
            if (mv < lmin) { lmin = mv; lidx = j; }
          }
        }
      } else {
        for (int j = tid; j < QQ; j += HT) {
          if (!used[j]) {
            const float cur = cost[((size_t)b * QQ + j) * TT + i0] - ui0 - v[j];
            float mv = minv[j];
            if (cur < mv) { mv = cur; minv[j] = cur; way[j] = j0; }
            if (mv < lmin) { lmin = mv; lidx = j; }
          }
        }
      }
      rv[tid] = lmin;
      ri[tid] = lidx;
      __syncthreads();
      for (int s = HT / 2; s > 0; s >>= 1) {
        if (tid < s) {
          const float ov = rv[tid + s];
          const int   oi = ri[tid + s];
          if (ov < rv[tid] || (ov == rv[tid] && oi < ri[tid])) {
            rv[tid] = ov;
            ri[tid] = oi;
          }
        }
        __syncthreads();
      }
      const float delta = rv[0];
      const int   j1    = ri[0];

      for (int j = tid; j < QQ; j += HT) {
        if (used[j]) {
          v[j] -= delta;
          u[p[j]] += delta;   // distinct rows per used column -> race-free
        } else {
          minv[j] -= delta;
        }
      }
      if (tid == 0) {
        u[p[QQ]] += delta;    // virtual column QQ is always used
        j0_s = j1;
      }
      __syncthreads();
    }

    // augment along the 'way' chain (serial, tiny)
    if (tid == 0) {
      int j0 = j0_s;
      while (j0 != QQ) {
        const int j1 = way[j0];
        p[j0] = p[j1];
        j0 = j1;
      }
    }
    __syncthreads();
  }

  // q_per_t: query assigned to each target row
  for (int j = tid; j < QQ; j += HT) {
    const int r = p[j];
    if (r < TT) qpt[r] = j;
  }
  __syncthreads();

  // argsort(q_per_t) via rank counting (values are distinct)
  if (tid < TT) {
    const int myq = qpt[tid];
    int rank = 0;
    for (int t2 = 0; t2 < TT; ++t2) rank += (qpt[t2] < myq) ? 1 : 0;
    out_q[b * TT + rank] = (float)myq;
    out_t[b * TT + rank] = (float)tid;
  }
}

extern "C" void kernel_launch(void* const* d_in, const int* in_sizes, int n_in,
                              void* d_out, int out_size, void* d_ws, size_t ws_size,
                              hipStream_t stream) {
  const float* logits  = (const float*)d_in[0];
  const float* pboxes  = (const float*)d_in[1];
  const int*   tlabels = (const int*)d_in[2];
  const float* tboxes  = (const float*)d_in[3];

  float* out  = (float*)d_out;
  float* cost = out;                               // [B][Q][T]
  float* oq   = out + (size_t)BB * QQ * TT;        // [B][T]
  float* ot   = oq + (size_t)BB * TT;              // [B][T]

  const size_t costT_bytes = (size_t)BB * TT * QQ * sizeof(float);
  float* costT = (ws_size >= costT_bytes) ? (float*)d_ws : nullptr;

  hipLaunchKernelGGL(cost_kernel, dim3(BB * QQ), dim3(128), 0, stream,
                     logits, pboxes, tlabels, tboxes, cost, costT);
  hipLaunchKernelGGL(hungarian_kernel, dim3(BB), dim3(HT), 0, stream,
                     cost, costT, oq, ot);
}

// Round 2
// 414.559 us; speedup vs baseline: 1.0005x; 1.0005x over previous
//
#include <hip/hip_runtime.h>

#define BB 16
#define QQ 900
#define CC 92
#define TT 100
#define INFF 1e18f
#define HT 256   // hungarian block threads

// ---------------- cost kernel: one block per (b,q) ----------------
__global__ __launch_bounds__(128) void cost_kernel(
    const float* __restrict__ logits,   // [B][Q][C]
    const float* __restrict__ pboxes,   // [B][Q][4]
    const int*   __restrict__ tlabels,  // [B][T]
    const float* __restrict__ tboxes,   // [B][T][4]
    float* __restrict__ cost,           // [B][Q][T]
    float* __restrict__ costT)          // [B][T][Q] or nullptr
{
  const int bq  = blockIdx.x;          // b*QQ + q
  const int b   = bq / QQ;
  const int q   = bq - b * QQ;
  const int tid = threadIdx.x;

  __shared__ float sl[CC];
  __shared__ float red[128];
  __shared__ float s_max, s_sum;

  float lv = (tid < CC) ? logits[(size_t)bq * CC + tid] : -3.402823466e38f;
  if (tid < CC) sl[tid] = lv;
  red[tid] = lv;
  __syncthreads();
  for (int s = 64; s > 0; s >>= 1) {
    if (tid < s) red[tid] = fmaxf(red[tid], red[tid + s]);
    __syncthreads();
  }
  if (tid == 0) s_max = red[0];
  __syncthreads();

  float e = (tid < CC) ? expf(lv - s_max) : 0.0f;
  if (tid < CC) sl[tid] = e;           // sl now holds exp(l - max)
  red[tid] = e;
  __syncthreads();
  for (int s = 64; s > 0; s >>= 1) {
    if (tid < s) red[tid] += red[tid + s];
    __syncthreads();
  }
  if (tid == 0) s_sum = red[0];
  __syncthreads();

  const float4 pbv = ((const float4*)pboxes)[bq];
  const float pax1 = pbv.x - 0.5f * pbv.z, pay1 = pbv.y - 0.5f * pbv.w;
  const float pax2 = pbv.x + 0.5f * pbv.z, pay2 = pbv.y + 0.5f * pbv.w;
  const float area_a = (pax2 - pax1) * (pay2 - pay1);
  const float ssum = s_sum;

  for (int t = tid; t < TT; t += 128) {
    const int lab = tlabels[b * TT + t];
    const float cc = -(sl[lab] / ssum);

    const float4 tb = ((const float4*)tboxes)[b * TT + t];
    const float cbox = fabsf(pbv.x - tb.x) + fabsf(pbv.y - tb.y) +
                       fabsf(pbv.z - tb.z) + fabsf(pbv.w - tb.w);

    const float bx1 = tb.x - 0.5f * tb.z, by1 = tb.y - 0.5f * tb.w;
    const float bx2 = tb.x + 0.5f * tb.z, by2 = tb.y + 0.5f * tb.w;
    const float area_b = (bx2 - bx1) * (by2 - by1);

    const float ltx = fmaxf(pax1, bx1), lty = fmaxf(pay1, by1);
    const float rbx = fminf(pax2, bx2), rby = fminf(pay2, by2);
    const float iw = fmaxf(rbx - ltx, 0.0f), ih = fmaxf(rby - lty, 0.0f);
    const float inter = iw * ih;
    const float uni = area_a + area_b - inter;
    const float iou = inter / uni;

    const float cx1 = fminf(pax1, bx1), cy1 = fminf(pay1, by1);
    const float cx2 = fmaxf(pax2, bx2), cy2 = fmaxf(pay2, by2);
    const float cw = fmaxf(cx2 - cx1, 0.0f), ch = fmaxf(cy2 - cy1, 0.0f);
    const float ac = cw * ch;
    const float giou = iou - (ac - uni) / ac;

    const float cval = 5.0f * cbox + cc - 2.0f * giou;
    cost[(size_t)bq * TT + t] = cval;
    if (costT) costT[((size_t)b * TT + t) * QQ + q] = cval;
  }
}

// ---------------- hungarian kernel: one block per batch ----------------
__global__ __launch_bounds__(HT) void hungarian_kernel(
    const float* __restrict__ cost,    // [B][Q][T]
    const float* __restrict__ costT,   // [B][T][Q] or nullptr
    float* __restrict__ out_q,         // [B][T]
    float* __restrict__ out_t)         // [B][T]
{
  const int b   = blockIdx.x;
  const int tid = threadIdx.x;

  __shared__ float v[QQ];
  __shared__ float u[TT + 1];
  __shared__ float minv[QQ];
  __shared__ int   way[QQ];
  __shared__ int   p[QQ + 1];
  __shared__ unsigned char used[QQ + 1];
  __shared__ int   qpt[TT];
  __shared__ float rv[HT];
  __shared__ int   ri[HT];
  __shared__ int   j0_s, i0_s, j1_s, done_s;

  for (int j = tid; j <= QQ; j += HT) {
    p[j] = TT;
    if (j < QQ) v[j] = 0.0f;
  }
  for (int i = tid; i <= TT; i += HT) u[i] = 0.0f;
  __syncthreads();

  for (int i = 0; i < TT; ++i) {
    if (tid == 0) { p[QQ] = i; j0_s = QQ; used[QQ] = 0; }
    for (int j = tid; j < QQ; j += HT) { minv[j] = INFF; way[j] = 0; used[j] = 0; }
    __syncthreads();

    while (true) {
      if (tid == 0) {
        const int j0 = j0_s;
        if (p[j0] == TT) {
          done_s = 1;
        } else {
          done_s = 0;
          used[j0] = 1;
          i0_s = p[j0];
        }
      }
      __syncthreads();
      if (done_s) break;

      const int   i0  = i0_s;
      const int   j0  = j0_s;
      const float ui0 = u[i0];

      float lmin = INFF;
      int   lidx = QQ;
      if (costT) {
        const float* __restrict__ crow = costT + ((size_t)b * TT + i0) * QQ;
        for (int j = tid; j < QQ; j += HT) {
          if (!used[j]) {
            const float cur = crow[j] - ui0 - v[j];
            float mv = minv[j];
            if (cur < mv) { mv = cur; minv[j] = cur; way[j] = j0; }
            if (mv < lmin) { lmin = mv; lidx = j; }
          }
        }
      } else {
        for (int j = tid; j < QQ; j += HT) {
          if (!used[j]) {
            const float cur = cost[((size_t)b * QQ + j) * TT + i0] - ui0 - v[j];
            float mv = minv[j];
            if (cur < mv) { mv = cur; minv[j] = cur; way[j] = j0; }
            if (mv < lmin) { lmin = mv; lidx = j; }
          }
        }
      }
      rv[tid] = lmin;
      ri[tid] = lidx;
      __syncthreads();
      for (int s = HT / 2; s > 0; s >>= 1) {
        if (tid < s) {
          const float ov = rv[tid + s];
          const int   oi = ri[tid + s];
          if (ov < rv[tid] || (ov == rv[tid] && oi < ri[tid])) {
            rv[tid] = ov;
            ri[tid] = oi;
          }
        }
        __syncthreads();
      }
      const float delta = rv[0];
      const int   j1    = ri[0];

      for (int j = tid; j < QQ; j += HT) {
        if (used[j]) {
          v[j] -= delta;
          u[p[j]] += delta;   // distinct rows per used column -> race-free
        } else {
          minv[j] -= delta;
        }
      }
      if (tid == 0) {
        u[p[QQ]] += delta;    // virtual column QQ is always used
        j0_s = j1;
      }
      __syncthreads();
    }

    // augment along the 'way' chain (serial, tiny)
    if (tid == 0) {
      int j0 = j0_s;
      while (j0 != QQ) {
        const int j1 = way[j0];
        p[j0] = p[j1];
        j0 = j1;
      }
    }
    __syncthreads();
  }

  // q_per_t: query assigned to each target row
  for (int j = tid; j < QQ; j += HT) {
    const int r = p[j];
    if (r < TT) qpt[r] = j;
  }
  __syncthreads();

  // argsort(q_per_t) via rank counting (values are distinct)
  if (tid < TT) {
    const int myq = qpt[tid];
    int rank = 0;
    for (int t2 = 0; t2 < TT; ++t2) rank += (qpt[t2] < myq) ? 1 : 0;
    out_q[b * TT + rank] = (float)myq;
    out_t[b * TT + rank] = (float)tid;
  }
}

extern "C" void kernel_launch(void* const* d_in, const int* in_sizes, int n_in,
                              void* d_out, int out_size, void* d_ws, size_t ws_size,
                              hipStream_t stream) {
  const float* logits  = (const float*)d_in[0];
  const float* pboxes  = (const float*)d_in[1];
  const int*   tlabels = (const int*)d_in[2];
  const float* tboxes  = (const float*)d_in[3];

  float* out  = (float*)d_out;
  float* cost = out;                               // [B][Q][T]
  float* oq   = out + (size_t)BB * QQ * TT;        // [B][T]
  float* ot   = oq + (size_t)BB * TT;              // [B][T]

  const size_t costT_bytes = (size_t)BB * TT * QQ * sizeof(float);
  float* costT = (ws_size >= costT_bytes) ? (float*)d_ws : nullptr;

  hipLaunchKernelGGL(cost_kernel, dim3(BB * QQ), dim3(128), 0, stream,
                     logits, pboxes, tlabels, tboxes, cost, costT);
  hipLaunchKernelGGL(hungarian_kernel, dim3(BB), dim3(HT), 0, stream,
                     cost, costT, oq, ot);
}

// Round 3
// 304.007 us; speedup vs baseline: 1.3644x; 1.3637x over previous
//
#include <hip/hip_runtime.h>

#define BB 16
#define QQ 900
#define CC 92
#define TT 100
#define INFF 1e18f
#define NK 15   // ceil(QQ / 64)

// ---------------- cost kernel: one block per (b,q) ----------------
__global__ __launch_bounds__(128) void cost_kernel(
    const float* __restrict__ logits,   // [B][Q][C]
    const float* __restrict__ pboxes,   // [B][Q][4]
    const int*   __restrict__ tlabels,  // [B][T]
    const float* __restrict__ tboxes,   // [B][T][4]
    float* __restrict__ cost,           // [B][Q][T]
    float* __restrict__ costT)          // [B][T][Q] or nullptr
{
  const int bq  = blockIdx.x;          // b*QQ + q
  const int b   = bq / QQ;
  const int q   = bq - b * QQ;
  const int tid = threadIdx.x;

  __shared__ float sl[CC];
  __shared__ float red[128];
  __shared__ float s_max, s_sum;

  float lv = (tid < CC) ? logits[(size_t)bq * CC + tid] : -3.402823466e38f;
  if (tid < CC) sl[tid] = lv;
  red[tid] = lv;
  __syncthreads();
  for (int s = 64; s > 0; s >>= 1) {
    if (tid < s) red[tid] = fmaxf(red[tid], red[tid + s]);
    __syncthreads();
  }
  if (tid == 0) s_max = red[0];
  __syncthreads();

  float e = (tid < CC) ? expf(lv - s_max) : 0.0f;
  if (tid < CC) sl[tid] = e;           // sl now holds exp(l - max)
  red[tid] = e;
  __syncthreads();
  for (int s = 64; s > 0; s >>= 1) {
    if (tid < s) red[tid] += red[tid + s];
    __syncthreads();
  }
  if (tid == 0) s_sum = red[0];
  __syncthreads();

  const float4 pbv = ((const float4*)pboxes)[bq];
  const float pax1 = pbv.x - 0.5f * pbv.z, pay1 = pbv.y - 0.5f * pbv.w;
  const float pax2 = pbv.x + 0.5f * pbv.z, pay2 = pbv.y + 0.5f * pbv.w;
  const float area_a = (pax2 - pax1) * (pay2 - pay1);
  const float ssum = s_sum;

  for (int t = tid; t < TT; t += 128) {
    const int lab = tlabels[b * TT + t];
    const float cc = -(sl[lab] / ssum);

    const float4 tb = ((const float4*)tboxes)[b * TT + t];
    const float cbox = fabsf(pbv.x - tb.x) + fabsf(pbv.y - tb.y) +
                       fabsf(pbv.z - tb.z) + fabsf(pbv.w - tb.w);

    const float bx1 = tb.x - 0.5f * tb.z, by1 = tb.y - 0.5f * tb.w;
    const float bx2 = tb.x + 0.5f * tb.z, by2 = tb.y + 0.5f * tb.w;
    const float area_b = (bx2 - bx1) * (by2 - by1);

    const float ltx = fmaxf(pax1, bx1), lty = fmaxf(pay1, by1);
    const float rbx = fminf(pax2, bx2), rby = fminf(pay2, by2);
    const float iw = fmaxf(rbx - ltx, 0.0f), ih = fmaxf(rby - lty, 0.0f);
    const float inter = iw * ih;
    const float uni = area_a + area_b - inter;
    const float iou = inter / uni;

    const float cx1 = fminf(pax1, bx1), cy1 = fminf(pay1, by1);
    const float cx2 = fmaxf(pax2, bx2), cy2 = fmaxf(pay2, by2);
    const float cw = fmaxf(cx2 - cx1, 0.0f), ch = fmaxf(cy2 - cy1, 0.0f);
    const float ac = cw * ch;
    const float giou = iou - (ac - uni) / ac;

    const float cval = 5.0f * cbox + cc - 2.0f * giou;
    cost[(size_t)bq * TT + t] = cval;
    if (costT) costT[((size_t)b * TT + t) * QQ + q] = cval;
  }
}

// ---------------- hungarian kernel: ONE WAVE per batch ----------------
// Column j (0..899) is owned by lane (j & 63), register slot (j >> 6).
// v / minv / cost-row / used-mask / matched-row all live in registers;
// only u (101), p (901), way (900) are in LDS. The 900-wide argmin is a
// 15-reg local min + 6 __shfl_xor steps: zero shared-mem reduction barriers.
__global__ __launch_bounds__(64) void hungarian_kernel(
    const float* __restrict__ cost,    // [B][Q][T]
    const float* __restrict__ costT,   // [B][T][Q] or nullptr
    float* __restrict__ out_q,         // [B][T]
    float* __restrict__ out_t)         // [B][T]
{
  const int b    = blockIdx.x;
  const int lane = threadIdx.x;

  __shared__ float u_lds[TT + 1];
  __shared__ int   p_lds[QQ + 1];
  __shared__ int   way_lds[QQ];
  __shared__ int   qpt[TT];

  // generic addressing: cost value(i0, j) = base[i0*rs + j*cs]
  const float* base;
  size_t rs, cs;
  if (costT) { base = costT + (size_t)b * TT * QQ; rs = QQ; cs = 1; }
  else       { base = cost  + (size_t)b * QQ * TT; rs = 1;  cs = TT; }

  for (int j = lane; j <= QQ; j += 64) p_lds[j] = TT;
  for (int t = lane; t <= TT; t += 64) u_lds[t] = 0.0f;

  float v[NK];
#pragma unroll
  for (int k = 0; k < NK; ++k) v[k] = 0.0f;
  __syncthreads();

  for (int i = 0; i < TT; ++i) {
    float minv[NK];
    int   rown[NK];
    unsigned umask = 0;
#pragma unroll
    for (int k = 0; k < NK; ++k) { minv[k] = INFF; rown[k] = 0; }

    if (lane == 0) p_lds[QQ] = i;
    __syncthreads();

    int i0 = i;     // p[j0] for virtual column j0 = QQ
    int j0 = QQ;

    // prefetch cost row i0
    float c[NK];
#pragma unroll
    for (int k = 0; k < NK; ++k) {
      const int j = k * 64 + lane;
      c[k] = (j < QQ) ? base[(size_t)i0 * rs + (size_t)j * cs] : 0.0f;
    }

    int jfin;
    while (true) {
      // mark column j0 as used (real columns only); its matched row is i0
      if (j0 < QQ) {
#pragma unroll
        for (int k = 0; k < NK; ++k) {
          if ((j0 >> 6) == k && (j0 & 63) == lane) {
            umask |= (1u << k);
            rown[k] = i0;
          }
        }
      }
      const float ui0 = u_lds[i0];

      // scan: update minv/way, track local min over unused columns
      float lmin = INFF;
      int   lidx = QQ;
#pragma unroll
      for (int k = 0; k < NK; ++k) {
        const int j = k * 64 + lane;
        if (j < QQ && !((umask >> k) & 1u)) {
          const float cur = c[k] - ui0 - v[k];
          if (cur < minv[k]) { minv[k] = cur; way_lds[j] = j0; }
          if (minv[k] < lmin) { lmin = minv[k]; lidx = j; }
        }
      }

      // wave argmin with lowest-index tie-break (matches jnp.argmin)
      float bv = lmin;
      int   bi = lidx;
#pragma unroll
      for (int s = 1; s < 64; s <<= 1) {
        const float ov = __shfl_xor(bv, s);
        const int   oi = __shfl_xor(bi, s);
        if (ov < bv || (ov == bv && oi < bi)) { bv = ov; bi = oi; }
      }
      const float delta = bv;
      const int   j1    = bi;

      const int  i0n = p_lds[j1];
      const bool fin = (i0n == TT);

      // prefetch next row (overlaps the update phase)
      if (!fin) {
#pragma unroll
        for (int k = 0; k < NK; ++k) {
          const int j = k * 64 + lane;
          if (j < QQ) c[k] = base[(size_t)i0n * rs + (size_t)j * cs];
        }
      }

      // potential updates: used -> v down / u up; unused -> minv down
#pragma unroll
      for (int k = 0; k < NK; ++k) {
        const int j = k * 64 + lane;
        if (j < QQ) {
          if ((umask >> k) & 1u) {
            v[k] -= delta;
            u_lds[rown[k]] += delta;  // distinct rows per used column
          } else {
            minv[k] -= delta;
          }
        }
      }
      if (lane == 0) u_lds[i] += delta;   // virtual column QQ: p[QQ] = i
      __syncthreads();                    // 1 wave: cheap; orders LDS RMWs

      if (fin) { jfin = j1; break; }
      j0 = j1;
      i0 = i0n;
    }

    // augment along the way chain (serial, tiny)
    if (lane == 0) {
      int j = jfin;
      while (j != QQ) {
        const int jn = way_lds[j];
        p_lds[j] = p_lds[jn];
        j = jn;
      }
    }
    __syncthreads();
  }

  // q_per_t: query assigned to each target row
#pragma unroll
  for (int k = 0; k < NK; ++k) {
    const int j = k * 64 + lane;
    if (j < QQ) {
      const int r = p_lds[j];
      if (r < TT) qpt[r] = j;
    }
  }
  __syncthreads();

  // argsort(q_per_t) via rank counting (values are distinct)
  for (int t = lane; t < TT; t += 64) {
    const int myq = qpt[t];
    int rank = 0;
    for (int t2 = 0; t2 < TT; ++t2) rank += (qpt[t2] < myq) ? 1 : 0;
    out_q[b * TT + rank] = (float)myq;
    out_t[b * TT + rank] = (float)t;
  }
}

extern "C" void kernel_launch(void* const* d_in, const int* in_sizes, int n_in,
                              void* d_out, int out_size, void* d_ws, size_t ws_size,
                              hipStream_t stream) {
  const float* logits  = (const float*)d_in[0];
  const float* pboxes  = (const float*)d_in[1];
  const int*   tlabels = (const int*)d_in[2];
  const float* tboxes  = (const float*)d_in[3];

  float* out  = (float*)d_out;
  float* cost = out;                               // [B][Q][T]
  float* oq   = out + (size_t)BB * QQ * TT;        // [B][T]
  float* ot   = oq + (size_t)BB * TT;              // [B][T]

  const size_t costT_bytes = (size_t)BB * TT * QQ * sizeof(float);
  float* costT = (ws_size >= costT_bytes) ? (float*)d_ws : nullptr;

  hipLaunchKernelGGL(cost_kernel, dim3(BB * QQ), dim3(128), 0, stream,
                     logits, pboxes, tlabels, tboxes, cost, costT);
  hipLaunchKernelGGL(hungarian_kernel, dim3(BB), dim3(64), 0, stream,
                     cost, costT, oq, ot);
}